// Round 1
// 116.292 us; speedup vs baseline: 1.0009x; 1.0009x over previous
//
#include <hip/hip_runtime.h>
#include <hip/hip_fp16.h>

// SuppLayer: out[b,c] = exp( sum_s x[b, cm[c,s]] * w[c,s] )
// B=4096, NCLASS=1000, NSUPP=64, NCHUNK=4096.
//
// R10: lo/hi split-tile pipeline + 8-quad-balanced 16B LDS slots.
//  - tile slot = 16 B = 8 rows fp16: tlo[idx] rows 0-7, thi[idx] rows 8-15
//    (64 KB each). Read bank-quad = idx&7 -> all 8 quads in play (R9's 32B
//    slots used only even quads => inherent 2x LDS serialization).
//  - pre-pass sort key widened (idx-c)&3 -> (idx-c)&7 to balance the 8
//    quads across a wave's 64 consecutive classes at each sg step.
//  - T14 async-stage split: after barrier 1, issue all 32 hi-row global
//    loads into regs, gather lo while they're in flight, then cvt+write
//    thi, barrier, store lo (overlaps hi gather), gather hi. Hides the
//    second half of the HBM stream under the lo gather.
//  - VGPR budget ~95 of 128 (hv 32 + acc 8 + d 16 + cm/w pipe + addr).

constexpr int B_       = 4096;
constexpr int NCLASS_  = 1000;
constexpr int NSUPP_   = 64;
constexpr int NCHUNK_  = 4096;
constexpr int BT       = 16;     // batch rows per block
constexpr int BH       = BT / 2; // rows per half-tile
constexpr int THREADS_ = 1024;
constexpr int SG_      = NSUPP_ / 4;            // 16 int4/float4 groups
constexpr size_t CMT_BYTES = (size_t)SG_ * NCLASS_ * 16;   // 256 KB
constexpr size_t WS_NEEDED = 2 * CMT_BYTES;                // 512 KB

// ---- pre-pass: one wave per class. Sort 64 (idx,w) by key=(idx-c)&7 and
// write to [sg][class] transposed layout. All-register rank computation. ----
__global__ __launch_bounds__(256)
void build_cw_kernel(const int*   __restrict__ cm,
                     const float* __restrict__ w,
                     int*         __restrict__ cmT,
                     float*       __restrict__ wT)
{
    const int t    = threadIdx.x;
    const int c    = blockIdx.x * 4 + (t >> 6);   // 4 classes per block
    const int lane = t & 63;
    if (c >= NCLASS_) return;                      // grid=250 -> never taken

    const int   idx = cm[c * NSUPP_ + lane];
    const float wv  = w [c * NSUPP_ + lane];
    const int   key = (idx - c) & 7;               // read quad = idx&7

    // stable rank of this element in sorted-by-key order
    const unsigned long long below = ((unsigned long long)1 << lane) - 1ull;
    int j = 0;
    #pragma unroll
    for (int r = 0; r < 8; ++r) {
        const unsigned long long m = __ballot(key == r);
        if (key > r)  j += __popcll(m);
        if (key == r) j += __popcll(m & below);
    }

    const int dst = ((j >> 2) * NCLASS_ + c) * 4 + (j & 3);
    cmT[dst] = idx;
    wT [dst] = wv;
}

// one half-tile gather: 16 sgs, 4 indices each, 1 ds_read_b128 per index
// (8 rows), one-deep cm/w prefetch pipeline through L2.
template <bool USET>
__device__ __forceinline__ void gather_half(
    const float4* __restrict__ t4,
    const float4* __restrict__ wT, const int4* __restrict__ cmT,
    const float* __restrict__ wSupp, const int* __restrict__ cmap,
    const int c, int4& ci, float4& wf, float acc[BH])
{
    for (int sg = 0; sg < SG_; ++sg) {
        // 4 independent ds_read_b128 issued up front
        float4 d0 = t4[ci.x], d1 = t4[ci.y], d2 = t4[ci.z], d3 = t4[ci.w];
        const float4 wv = wf;

        // prefetch next group's cm/w (L2) past this group's math
        const int sgn = (sg + 1 < SG_) ? sg + 1 : SG_ - 1;
        if constexpr (USET) {
            ci = cmT[sgn * NCLASS_ + c];
            wf = wT [sgn * NCLASS_ + c];
        } else {
            ci = reinterpret_cast<const int4*>(cmap + c * NSUPP_)[sgn];
            wf = reinterpret_cast<const float4*>(wSupp + c * NSUPP_)[sgn];
        }

        const float4* dp[4]  = {&d0, &d1, &d2, &d3};
        const float   ws4[4] = {wv.x, wv.y, wv.z, wv.w};
        #pragma unroll
        for (int j = 0; j < 4; ++j) {
            const __half2* h = reinterpret_cast<const __half2*>(dp[j]);
            #pragma unroll
            for (int k = 0; k < 4; ++k) {
                const float2 f = __half22float2(h[k]);
                acc[2 * k]     = fmaf(f.x, ws4[j], acc[2 * k]);
                acc[2 * k + 1] = fmaf(f.y, ws4[j], acc[2 * k + 1]);
            }
        }
    }
}

template <bool USET>
__global__ __launch_bounds__(THREADS_, 4)
void supp_gather_kernel(const float* __restrict__ x,
                        const float* __restrict__ wSupp,
                        const int*   __restrict__ cmap,
                        const float4* __restrict__ wT,
                        const int4*   __restrict__ cmT,
                        float*       __restrict__ out)
{
    // two 64 KB halves; slot idx = 16 B = 8 rows as half2 pairs
    __shared__ __align__(16) __half2 tile[NCHUNK_ * 8];
    __half2* tlo = tile;
    __half2* thi = tile + NCHUNK_ * 4;

    const int t  = threadIdx.x;
    const int rb = blockIdx.x * BT;   // first batch row of this tile

    // ---- prefetch first cm/w group before staging (hide L2 latency) ----
    int4   ci;
    float4 wf;
    if (t < NCLASS_) {
        if constexpr (USET) { ci = cmT[t]; wf = wT[t]; }
        else {
            ci = reinterpret_cast<const int4*>(cmap + t * NSUPP_)[0];
            wf = reinterpret_cast<const float4*>(wSupp + t * NSUPP_)[0];
        }
    }

    // ---- phase 1: stage rows rb..rb+7 -> fp16 -> tlo ----
    // thread t owns cols col = t + 1024p; consecutive lanes write
    // consecutive 16B slots -> all 8 quads cycle, conflict-free.
    #pragma unroll
    for (int p = 0; p < NCHUNK_ / THREADS_; ++p) {
        const int col = t + THREADS_ * p;
        float v[BH];
        #pragma unroll
        for (int bi = 0; bi < BH; ++bi)
            v[bi] = x[(size_t)(rb + bi) * NCHUNK_ + col];
        __half2 h[BH / 2];
        #pragma unroll
        for (int k = 0; k < BH / 2; ++k)
            h[k] = __floats2half2_rn(v[2 * k], v[2 * k + 1]);
        *reinterpret_cast<float4*>(&tlo[(size_t)col * 4]) =
            *reinterpret_cast<const float4*>(&h[0]);
    }
    __syncthreads();

    // ---- phase 2: issue hi-row loads to regs (T14), gather lo under them ----
    float hv[4 * BH];
    #pragma unroll
    for (int p = 0; p < NCHUNK_ / THREADS_; ++p) {
        const int col = t + THREADS_ * p;
        #pragma unroll
        for (int bi = 0; bi < BH; ++bi)
            hv[p * BH + bi] = x[(size_t)(rb + BH + bi) * NCHUNK_ + col];
    }
    // pin the loads here — don't let the scheduler sink them past the gather
    __builtin_amdgcn_sched_barrier(0);

    float accl[BH];
    if (t < NCLASS_) {
        #pragma unroll
        for (int bi = 0; bi < BH; ++bi) accl[bi] = 0.f;
        gather_half<USET>(reinterpret_cast<const float4*>(tlo),
                          wT, cmT, wSupp, cmap, t, ci, wf, accl);
    }

    // ---- convert + write hi tile (vmcnt waits only on hv loads) ----
    #pragma unroll
    for (int p = 0; p < NCHUNK_ / THREADS_; ++p) {
        const int col = t + THREADS_ * p;
        __half2 h[BH / 2];
        #pragma unroll
        for (int k = 0; k < BH / 2; ++k)
            h[k] = __floats2half2_rn(hv[p * BH + 2 * k], hv[p * BH + 2 * k + 1]);
        *reinterpret_cast<float4*>(&thi[(size_t)col * 4]) =
            *reinterpret_cast<const float4*>(&h[0]);
    }
    // re-prime cm/w pipeline for the hi pass (L2-warm, hidden by barrier)
    if (t < NCLASS_) {
        if constexpr (USET) { ci = cmT[t]; wf = wT[t]; }
        else {
            ci = reinterpret_cast<const int4*>(cmap + t * NSUPP_)[0];
            wf = reinterpret_cast<const float4*>(wSupp + t * NSUPP_)[0];
        }
    }
    __syncthreads();

    // ---- phase 3: store lo (overlaps hi gather), gather hi, store hi ----
    if (t < NCLASS_) {
        const int c = t;
        #pragma unroll
        for (int bi = 0; bi < BH; ++bi)
            out[(size_t)(rb + bi) * NCLASS_ + c] = __expf(accl[bi]);

        float acch[BH];
        #pragma unroll
        for (int bi = 0; bi < BH; ++bi) acch[bi] = 0.f;
        gather_half<USET>(reinterpret_cast<const float4*>(thi),
                          wT, cmT, wSupp, cmap, c, ci, wf, acch);

        #pragma unroll
        for (int bi = 0; bi < BH; ++bi)
            out[(size_t)(rb + BH + bi) * NCLASS_ + c] = __expf(acch[bi]);
    }
}

extern "C" void kernel_launch(void* const* d_in, const int* in_sizes, int n_in,
                              void* d_out, int out_size, void* d_ws, size_t ws_size,
                              hipStream_t stream) {
    const float* x  = (const float*)d_in[0];   // (B, NCHUNK) fp32
    const float* w  = (const float*)d_in[1];   // (NCLASS, NSUPP) fp32
    const int*   cm = (const int*)d_in[2];     // (NCLASS, NSUPP) int32
    float*       o  = (float*)d_out;           // (B, NCLASS) fp32

    int*   cmT = (int*)d_ws;
    float* wT  = (float*)((char*)d_ws + CMT_BYTES);

    const dim3 grid(B_ / BT);                  // 256 blocks
    if (ws_size >= WS_NEEDED) {
        build_cw_kernel<<<dim3((NCLASS_ + 3) / 4), dim3(256), 0, stream>>>(
            cm, w, cmT, wT);
        supp_gather_kernel<true><<<grid, dim3(THREADS_), 0, stream>>>(
            x, w, cm, (const float4*)wT, (const int4*)cmT, o);
    } else {
        supp_gather_kernel<false><<<grid, dim3(THREADS_), 0, stream>>>(
            x, w, cm, (const float4*)wT, (const int4*)cmT, o);
    }
}